// Round 1
// baseline (165.227 us; speedup 1.0000x reference)
//
#include <hip/hip_runtime.h>

// Problem: unbiased EWMA mean/var normalization over T, s:(16,2000,257,2) fp32.
// Layout: idx = ((n*T + t)*F + f)*C + c  ->  series stride over t is F*C = 514.
//
// Strategy (v2 — TLP + table):
//  - One thread per (n,f,c) series slice; sequential over t (clamp S>0 breaks
//    scan associativity, so no exact parallel scan).
//  - Chunk T into NCHUNK=16 chunks of CLEN=125 (exact) with WARM=512 warm-up
//    steps (state error decays by beta^512 ~ 5.9e-3; chunks 0-4 start exactly
//    at t=0). 16 chunks * 129 wave-blocks = 2064 waves ~= 2.0 waves/SIMD:
//    previous 903-wave config (0.88/SIMD) was latency-bound at ~240 cyc/step
//    vs ~32 cyc/step issue (VALUBusy 20%, occupancy 7.4%). Two waves/SIMD
//    lets the scheduler hide the recurrence + memory latency.
//  - t-dependent, lane-invariant scalars r=1/(1-beta^{t+1}), w=(1-beta)*r are
//    precomputed per-block into an LDS table (broadcast ds_read_b64/step),
//    removing 1 transcendental + 3 VALU/step and taking rcp off the chain.
//  - Recurrent chains shortened to 1 fma each:
//      v1 = fma(beta, v1, (1-beta)*x);  S = fma(S, 1-w, w*pr)  (+fmax clamp).
//  - Register prefetch ring of PF=16 timesteps hides load latency within a
//    wave; the second wave per SIMD hides the rest.

#define NN 16
#define TT 2000
#define FCC 514               // F*C
#define SERIES (NN * FCC)     // 8224
#define BETAF 0.99f
#define OMBF 0.01f            // 1 - beta
#define EPSF 1e-5f
#define NCHUNK 16
#define CLEN 125              // 16 * 125 = 2000 exact
#define WARM 512
#define PF 16
#define TABMAX (WARM + CLEN)  // 637 entries max

__global__ __launch_bounds__(64)
void ewma_kernel(const float* __restrict__ s, float* __restrict__ out) {
    __shared__ float2 tab[TABMAX];   // {r_t, w_t} for t = t0..t_end-1

    const int chunk = blockIdx.y;
    const int t_out = chunk * CLEN;
    int t_end = t_out + CLEN; if (t_end > TT) t_end = TT;
    int t0 = t_out - WARM;     if (t0 < 0) t0 = 0;
    const int L = t_end - t0;

    // Build the r/w table: exact beta^(t+1) via double binary exponentiation
    // (one-time; ~10 entries/lane, 11 squarings each).
    for (int i = threadIdx.x; i < L; i += 64) {
        double bd = 0.99, acc = 1.0;
        int e = t0 + i + 1;            // reference uses beta^(t+1) at row t
        #pragma unroll
        for (int k = 0; k < 11; ++k) { if (e & 1) acc *= bd; bd *= bd; e >>= 1; }
        const float om = 1.0f - (float)acc;          // 1 - beta^{t+1}
        const float r  = __builtin_amdgcn_rcpf(om);  // 1 ulp; threshold is 0.1
        tab[i] = make_float2(r, OMBF * r);
    }
    __syncthreads();
    // single sync above; safe to early-exit now

    const int tid = blockIdx.x * 64 + threadIdx.x;
    if (tid >= SERIES) return;

    const int n  = tid / FCC;
    const int fc = tid - n * FCC;

    float v1 = 0.0f, v2p = 0.0f, S = 0.0f;

    const size_t base = (size_t)n * TT * FCC + (size_t)fc + (size_t)t0 * FCC;
    const float* p  = s   + base;
    float*       po = out + base;

    auto step = [&](float x, float2 rw) -> float {
        const float r = rw.x, w = rw.y;
        v1 = fmaf(BETAF, v1, OMBF * x);        // chain: 1 fma
        const float v2  = v1 * r;
        const float d   = x - v2;
        const float dp  = x - v2p;
        const float wpr = w * (d * dp);        // off-chain
        S = fmaf(S, 1.0f - w, wpr);            // chain: 1 fma
        S = fmaxf(S, 0.0f);
        const float y = d * __builtin_amdgcn_rsqf(S + EPSF);  // leaf, off-chain
        v2p = v2;
        return y;
    };

    // initial fill (every chunk has >= CLEN=125 >= PF steps)
    float buf[PF];
    #pragma unroll
    for (int i = 0; i < PF; ++i) buf[i] = p[i * FCC];

    int t = t0;
    int li = 0;                       // local table index (t - t0)
    while (t + PF <= t_end) {
        // prefetch next group's 16 values (clamped in-bounds re-read when the
        // next group doesn't exist; values then unused since loop exits)
        const float* pf_ptr = (t + 2 * PF <= t_end) ? (p + PF * FCC) : p;
        float nbuf[PF];
        #pragma unroll
        for (int i = 0; i < PF; ++i) nbuf[i] = pf_ptr[i * FCC];

        #pragma unroll
        for (int i = 0; i < PF; ++i) {
            const float y = step(buf[i], tab[li + i]);
            if (t >= t_out) {                 // loop-invariant: full-output group
                po[i * FCC] = y;
            } else if (t + i >= t_out) {      // mixed warmup/output boundary group
                po[i * FCC] = y;
            }
        }

        #pragma unroll
        for (int i = 0; i < PF; ++i) buf[i] = nbuf[i];
        p  += PF * FCC;
        po += PF * FCC;
        t  += PF;
        li += PF;
    }
    // tail (< PF steps)
    for (; t < t_end; ++t, ++li) {
        const float y = step(*p, tab[li]);
        if (t >= t_out) *po = y;
        p  += FCC;
        po += FCC;
    }
}

extern "C" void kernel_launch(void* const* d_in, const int* in_sizes, int n_in,
                              void* d_out, int out_size, void* d_ws, size_t ws_size,
                              hipStream_t stream) {
    const float* s = (const float*)d_in[0];
    float* out = (float*)d_out;
    dim3 grid((SERIES + 63) / 64, NCHUNK);   // 129 x 16 blocks of 64
    ewma_kernel<<<grid, dim3(64), 0, stream>>>(s, out);
}

// Round 3
// 153.443 us; speedup vs baseline: 1.0768x; 1.0768x over previous
//
#include <hip/hip_runtime.h>

// Problem: unbiased EWMA mean/var normalization over T, s:(16,2000,257,2) fp32.
// Layout: idx = ((n*T + t)*F + f)*C + c  ->  series stride over t is F*C = 514.
//
// Strategy (v3b — make the prefetch REAL; resubmit after infra failure):
//  - One thread per (n,f,c) series; sequential over t (S>0 clamp breaks scan
//    associativity -> no exact parallel scan).
//  - NCHUNK=7 chunks of CLEN=286, WARM=512 (beta^512 ~ 5.9e-3). 903 waves ->
//    1 wave/SIMD, lowest warm-redundancy traffic (~180 MB -> ~29 us floor).
//    v2's 16-chunk TLP experiment showed TLP does NOT pay: per-wave step cost
//    was 238-315 cyc because the register prefetch was silently folded into
//    just-in-time loads (VGPR_Count=24 < the 32 floats of buf+nbuf!) --
//    every step ate a full L2/L3 latency.
//  - v3 pins the 16-deep prefetch: sched_barrier(0) after load issue keeps
//    the loads at the top of the group; asm "+v" value-pins before the buf
//    copy keep them live (un-foldable) and put the vmcnt wait AFTER compute.
//  - No LDS (v2's per-step ds_read added ~80 cyc/step of lgkm stalls at low
//    occupancy). Lane-invariant r=1/(1-beta^{t+1}), w=(1-beta)*r computed per
//    16-group into registers: 16 independent pipelined v_rcp, off-chain.
//  - Recurrent chains: v1 = fma(beta,v1,omb*x) (4 cyc/step); S: sub+fma+max.
//  - Nontemporal stores: output is never re-read; keep L2/L3 for warm reads.

#define NN 16
#define TT 2000
#define FCC 514               // F*C
#define SERIES (NN * FCC)     // 8224
#define BETAF 0.99f
#define OMBF 0.01f            // 1 - beta
#define EPSF 1e-5f
#define NCHUNK 7
#define CLEN 286              // ceil(2000/7)
#define WARM 512
#define PF 16

// beta^i, i=0..16 (compile-time literals)
__device__ __constant__ const float BP[PF + 1] = {
    1.0f,
    0.99f,
    0.9801f,
    0.970299f,
    0.96059601f,
    0.9509900499f,
    0.941480149401f,
    0.93206534790699f,
    0.9227446944279201f,
    0.9134272474836409f,
    0.9042929750088045f,
    0.8952500452587165f,
    0.8862975448061293f,
    0.877434569357868f,
    0.8686602236642894f,
    0.8599736214276465f,
    0.8513738852133700f   // beta^16 (per-group btg advance)
};

__global__ __launch_bounds__(64)
void ewma_kernel(const float* __restrict__ s, float* __restrict__ out) {
    const int tid = blockIdx.x * 64 + threadIdx.x;
    if (tid >= SERIES) return;

    const int chunk = blockIdx.y;
    const int t_out = chunk * CLEN;
    int t_end = t_out + CLEN; if (t_end > TT) t_end = TT;
    int t0 = t_out - WARM;     if (t0 < 0) t0 = 0;

    const int n  = tid / FCC;
    const int fc = tid - n * FCC;

    // btg = beta^(t0+1) via double binary exponentiation (once per thread)
    double bd = 0.99, acc = 0.99;       // acc starts at beta^1
    int e = t0;
    while (e) { if (e & 1) acc *= bd; bd *= bd; e >>= 1; }
    float btg = (float)acc;             // beta^(t+1) for the group's first step

    float v1 = 0.0f, v2p = 0.0f, S = 0.0f;

    const size_t base = (size_t)n * TT * FCC + (size_t)fc + (size_t)t0 * FCC;
    const float* p  = s   + base;
    float*       po = out + base;

    // initial fill (every chunk has >= CLEN=286 >= PF steps)
    float buf[PF];
    #pragma unroll
    for (int i = 0; i < PF; ++i) buf[i] = p[i * FCC];

    int t = t0;
    while (t + PF <= t_end) {
        // ---- issue next group's 16 loads (stay at top: sched_barrier) ----
        const float* pf_ptr = (t + 2 * PF <= t_end) ? (p + PF * FCC) : p;
        float nbuf[PF];
        #pragma unroll
        for (int i = 0; i < PF; ++i) nbuf[i] = pf_ptr[i * FCC];
        __builtin_amdgcn_sched_barrier(0);

        // ---- per-group lane-invariant scalars, batched into registers ----
        float rr[PF], ww[PF];
        #pragma unroll
        for (int i = 0; i < PF; ++i) {
            const float bt = btg * BP[i];               // beta^(t+1+i)
            const float om = 1.0f - bt;
            const float r  = __builtin_amdgcn_rcpf(om); // 1 ulp; tol is 0.1
            rr[i] = r;
            ww[i] = OMBF * r;
        }
        btg *= BP[PF];

        // ---- 16 steps on the previous group's (pinned) data ----
        #pragma unroll
        for (int i = 0; i < PF; ++i) {
            const float x  = buf[i];
            v1 = fmaf(BETAF, v1, OMBF * x);             // chain: 1 fma
            const float v2 = v1 * rr[i];
            const float d  = x - v2;
            const float dp = x - v2p;
            const float pr = d * dp;
            S = fmaf(ww[i], pr - S, S);                 // (1-w)*S + w*pr
            S = fmaxf(S, 0.0f);
            const float y = d * __builtin_amdgcn_rsqf(S + EPSF);
            v2p = v2;
            if (t >= t_out) {                  // full-output group (uniform)
                __builtin_nontemporal_store(y, po + i * FCC);
            } else if (t + i >= t_out) {       // warmup/output boundary group
                __builtin_nontemporal_store(y, po + i * FCC);
            }
        }

        // ---- pin loads live; vmcnt wait lands HERE (after compute) ----
        #pragma unroll
        for (int i = 0; i < PF; ++i) {
            asm volatile("" : "+v"(nbuf[i]));
            buf[i] = nbuf[i];
        }
        p  += PF * FCC;
        po += PF * FCC;
        t  += PF;
    }
    // tail (< PF steps)
    for (; t < t_end; ++t) {
        const float x  = *p;
        const float om = 1.0f - btg;
        const float r  = __builtin_amdgcn_rcpf(om);
        const float w  = OMBF * r;
        btg *= BETAF;
        v1 = fmaf(BETAF, v1, OMBF * x);
        const float v2 = v1 * r;
        const float d  = x - v2;
        const float dp = x - v2p;
        const float pr = d * dp;
        S = fmaf(w, pr - S, S);
        S = fmaxf(S, 0.0f);
        const float y = d * __builtin_amdgcn_rsqf(S + EPSF);
        v2p = v2;
        if (t >= t_out) __builtin_nontemporal_store(y, po);
        p  += FCC;
        po += FCC;
    }
}

extern "C" void kernel_launch(void* const* d_in, const int* in_sizes, int n_in,
                              void* d_out, int out_size, void* d_ws, size_t ws_size,
                              hipStream_t stream) {
    const float* s = (const float*)d_in[0];
    float* out = (float*)d_out;
    dim3 grid((SERIES + 63) / 64, NCHUNK);   // 129 x 7 blocks of 64
    ewma_kernel<<<grid, dim3(64), 0, stream>>>(s, out);
}

// Round 4
// 151.315 us; speedup vs baseline: 1.0919x; 1.0141x over previous
//
#include <hip/hip_runtime.h>

// Problem: unbiased EWMA mean/var normalization over T, s:(16,2000,257,2) fp32.
// Layout: idx = ((n*T + t)*F + f)*C + c  ->  series stride over t is F*C = 514.
//
// Strategy (v4 — force the prefetch with inline asm + full RA budget):
//  - One thread per (n,f,c) series; sequential over t (S>0 clamp breaks scan
//    associativity -> no exact parallel scan).
//  - NCHUNK=7 chunks of CLEN=286, WARM=512 (beta^512 ~ 5.9e-3). 903 waves ->
//    ~0.88 wave/SIMD, lowest warm-redundancy traffic (~180 MB -> ~29 us floor).
//  - v1-v3 post-mortem: VGPR_Count=24 in ALL versions -- the compiler's
//    pressure-minimizing scheduler folded every register-prefetch attempt
//    into ~4-wide just-in-time load batches; each batch pays full HBM/L2
//    latency => 222 cyc/step observed (~900cyc/4). Source-level pins
//    (sched_barrier + "+v" asm) did NOT survive RA.
//  - v4 fixes the root cause twice over:
//      (a) amdgpu_waves_per_eu(1,1): we run <=1 wave/SIMD anyway; give RA the
//          full register budget and remove its motive to minimize pressure.
//      (b) the 16 prefetch loads are volatile inline-asm global_load_dword
//          with "=v" outputs consumed only after the compute block -- the
//          compiler cannot fold/sink/batch them. Explicit s_waitcnt vmcnt(0)
//          + sched_barrier(0) (rule: hoisting past asm waitcnt) places the
//          single wait AFTER the group's compute. 16 loads overlap ~300 cyc
//          of compute; per-step latency cost drops ~15x.
//  - Compiler-tracked ops (initial fill, tail, stores) under-count the asm
//    loads in their vmcnt model -> their auto-waits are only ever STRONGER
//    than needed. Safe.
//  - Lane-invariant r=1/(1-beta^{t+1}), w=(1-beta)*r batched per group (16
//    independent pipelined v_rcp, off the recurrent chain).
//  - Nontemporal stores: output never re-read; keep L2/L3 for warm reads.

#define NN 16
#define TT 2000
#define FCC 514               // F*C
#define SERIES (NN * FCC)     // 8224
#define BETAF 0.99f
#define OMBF 0.01f            // 1 - beta
#define EPSF 1e-5f
#define NCHUNK 7
#define CLEN 286              // ceil(2000/7)
#define WARM 512
#define PF 16

// beta^i, i=0..16 (compile-time literals)
__device__ __constant__ const float BP[PF + 1] = {
    1.0f,
    0.99f,
    0.9801f,
    0.970299f,
    0.96059601f,
    0.9509900499f,
    0.941480149401f,
    0.93206534790699f,
    0.9227446944279201f,
    0.9134272474836409f,
    0.9042929750088045f,
    0.8952500452587165f,
    0.8862975448061293f,
    0.877434569357868f,
    0.8686602236642894f,
    0.8599736214276465f,
    0.8513738852133700f   // beta^16 (per-group btg advance)
};

__global__ __launch_bounds__(64) __attribute__((amdgpu_waves_per_eu(1, 1)))
void ewma_kernel(const float* __restrict__ s, float* __restrict__ out) {
    const int tid = blockIdx.x * 64 + threadIdx.x;
    if (tid >= SERIES) return;

    const int chunk = blockIdx.y;
    const int t_out = chunk * CLEN;
    int t_end = t_out + CLEN; if (t_end > TT) t_end = TT;
    int t0 = t_out - WARM;     if (t0 < 0) t0 = 0;

    const int n  = tid / FCC;
    const int fc = tid - n * FCC;

    // btg = beta^(t0+1) via double binary exponentiation (once per thread)
    double bd = 0.99, acc = 0.99;       // acc starts at beta^1
    int e = t0;
    while (e) { if (e & 1) acc *= bd; bd *= bd; e >>= 1; }
    float btg = (float)acc;             // beta^(t+1) for the group's first step

    float v1 = 0.0f, v2p = 0.0f, S = 0.0f;

    const size_t base = (size_t)n * TT * FCC + (size_t)fc + (size_t)t0 * FCC;
    const float* p  = s   + base;
    float*       po = out + base;

    // initial fill (every chunk has >= CLEN=286 >= PF steps); compiler loads,
    // compiler-inserted waits (conservative vs our asm loads -> safe).
    float buf[PF];
    #pragma unroll
    for (int i = 0; i < PF; ++i) buf[i] = p[i * FCC];

    int t = t0;
    while (t + PF <= t_end) {
        // ---- issue next group's 16 loads: opaque volatile asm, un-foldable.
        const float* pf_ptr = (t + 2 * PF <= t_end) ? (p + PF * FCC) : p;
        float nbuf[PF];
        #pragma unroll
        for (int i = 0; i < PF; ++i) {
            asm volatile("global_load_dword %0, %1, off"
                         : "=v"(nbuf[i])
                         : "v"(pf_ptr + i * FCC));
        }
        __builtin_amdgcn_sched_barrier(0);   // pin issue at group top

        // ---- per-group lane-invariant scalars (off-chain, pipelined rcp)
        float rr[PF], ww[PF];
        #pragma unroll
        for (int i = 0; i < PF; ++i) {
            const float bt = btg * BP[i];               // beta^(t+1+i)
            const float om = 1.0f - bt;
            const float r  = __builtin_amdgcn_rcpf(om); // 1 ulp; tol is 0.1
            rr[i] = r;
            ww[i] = OMBF * r;
        }
        btg *= BP[PF];

        // ---- 16 steps on the previous group's (register-resident) data ----
        #pragma unroll
        for (int i = 0; i < PF; ++i) {
            const float x  = buf[i];
            v1 = fmaf(BETAF, v1, OMBF * x);             // chain: 1 fma
            const float v2 = v1 * rr[i];
            const float d  = x - v2;
            const float dp = x - v2p;
            const float pr = d * dp;
            S = fmaf(ww[i], pr - S, S);                 // (1-w)*S + w*pr
            S = fmaxf(S, 0.0f);
            const float y = d * __builtin_amdgcn_rsqf(S + EPSF);
            v2p = v2;
            if (t >= t_out) {                  // full-output group (uniform)
                __builtin_nontemporal_store(y, po + i * FCC);
            } else if (t + i >= t_out) {       // warmup/output boundary group
                __builtin_nontemporal_store(y, po + i * FCC);
            }
        }

        // ---- single wait for the 16 asm loads, AFTER compute ----
        asm volatile("s_waitcnt vmcnt(0)" ::: "memory");
        __builtin_amdgcn_sched_barrier(0);   // nothing hoists above the wait
        #pragma unroll
        for (int i = 0; i < PF; ++i) buf[i] = nbuf[i];

        p  += PF * FCC;
        po += PF * FCC;
        t  += PF;
    }
    // tail (< PF steps): plain compiler-managed loads (asm loads all drained)
    for (; t < t_end; ++t) {
        const float x  = *p;
        const float om = 1.0f - btg;
        const float r  = __builtin_amdgcn_rcpf(om);
        const float w  = OMBF * r;
        btg *= BETAF;
        v1 = fmaf(BETAF, v1, OMBF * x);
        const float v2 = v1 * r;
        const float d  = x - v2;
        const float dp = x - v2p;
        const float pr = d * dp;
        S = fmaf(w, pr - S, S);
        S = fmaxf(S, 0.0f);
        const float y = d * __builtin_amdgcn_rsqf(S + EPSF);
        v2p = v2;
        if (t >= t_out) __builtin_nontemporal_store(y, po);
        p  += FCC;
        po += FCC;
    }
}

extern "C" void kernel_launch(void* const* d_in, const int* in_sizes, int n_in,
                              void* d_out, int out_size, void* d_ws, size_t ws_size,
                              hipStream_t stream) {
    const float* s = (const float*)d_in[0];
    float* out = (float*)d_out;
    dim3 grid((SERIES + 63) / 64, NCHUNK);   // 129 x 7 blocks of 64
    ewma_kernel<<<grid, dim3(64), 0, stream>>>(s, out);
}

// Round 5
// 150.600 us; speedup vs baseline: 1.0971x; 1.0047x over previous
//
#include <hip/hip_runtime.h>

// Problem: unbiased EWMA mean/var normalization over T, s:(16,2000,257,2) fp32.
// Layout: idx = ((n*T + t)*F + f)*C + c  ->  series stride over t is F*C = 514.
//
// Strategy (v5 — counted vmcnt: never drain the stores):
//  - One thread per (n,f,c) series; sequential over t (S>0 clamp breaks scan
//    associativity -> no exact parallel scan).
//  - NCHUNK=7 chunks of CLEN=286, WARM=512 (beta^512 ~ 5.9e-3). 903 waves.
//  - v4 post-mortem: VGPR=132 proved the 16-deep asm prefetch is real, yet
//    dur stayed 71.7us = 3440 cyc/group vs ~700 compute. The group's
//    s_waitcnt vmcnt(0) was draining the 16 NONTEMPORAL STORES too -- each
//    group serialized on a store-ack round trip (~1.4us under congestion;
//    Little's law: 903 waves * 4KB * stall-fraction / 375ns = 2.6 TB/s =
//    exactly the measured hbm_gbps).
//  - v5: counted waits (CUDA cp.async.wait_group analog). Per output group:
//    issue 16 asm loads (pinned at top), compute + 16 volatile-asm NT stores
//    (volatile asms keep program order -> loads are the 16 OLDEST), then
//    s_waitcnt vmcnt(16): completes all loads + last group's store leftovers,
//    leaves this group's 16 stores in flight. Stores get a full group of
//    compute+load time to retire -- never a drain in the main loop.
//  - Loop split warm/boundary/output so the outstanding-op count at each
//    wait is deterministic: warm has no stores (vmcnt(0) = loads only; y
//    dead-codes away), boundary (1 group/chunk, conditional stores) uses a
//    conservative vmcnt(0).
//  - Compiler-tracked ops (prologue fill, tail) don't know about the asm
//    loads/stores, but untracked ops are always OLDER than tracked ones ->
//    compiler-inserted waits are only ever stronger than intended. Safe.
//  - Lane-invariant r=1/(1-beta^{t+1}), w=(1-beta)*r batched per group (16
//    pipelined v_rcp, off the recurrent chain). waves_per_eu(1,1) keeps the
//    full VGPR budget unlocked.

#define NN 16
#define TT 2000
#define FCC 514               // F*C
#define SERIES (NN * FCC)     // 8224
#define BETAF 0.99f
#define OMBF 0.01f            // 1 - beta
#define EPSF 1e-5f
#define NCHUNK 7
#define CLEN 286              // ceil(2000/7)
#define WARM 512
#define PF 16

// beta^i, i=0..16 (compile-time literals)
__device__ __constant__ const float BP[PF + 1] = {
    1.0f,
    0.99f,
    0.9801f,
    0.970299f,
    0.96059601f,
    0.9509900499f,
    0.941480149401f,
    0.93206534790699f,
    0.9227446944279201f,
    0.9134272474836409f,
    0.9042929750088045f,
    0.8952500452587165f,
    0.8862975448061293f,
    0.877434569357868f,
    0.8686602236642894f,
    0.8599736214276465f,
    0.8513738852133700f   // beta^16 (per-group btg advance)
};

__global__ __launch_bounds__(64) __attribute__((amdgpu_waves_per_eu(1, 1)))
void ewma_kernel(const float* __restrict__ s, float* __restrict__ out) {
    const int tid = blockIdx.x * 64 + threadIdx.x;
    if (tid >= SERIES) return;

    const int chunk = blockIdx.y;
    const int t_out = chunk * CLEN;
    int t_end = t_out + CLEN; if (t_end > TT) t_end = TT;
    int t0 = t_out - WARM;     if (t0 < 0) t0 = 0;

    const int n  = tid / FCC;
    const int fc = tid - n * FCC;

    // btg = beta^(t0+1) via double binary exponentiation (once per thread)
    double bd = 0.99, acc = 0.99;       // acc starts at beta^1
    int e = t0;
    while (e) { if (e & 1) acc *= bd; bd *= bd; e >>= 1; }
    float btg = (float)acc;             // beta^(t+1) for the group's first step

    float v1 = 0.0f, v2p = 0.0f, S = 0.0f;

    const size_t base = (size_t)n * TT * FCC + (size_t)fc + (size_t)t0 * FCC;
    const float* p  = s   + base;
    float*       po = out + base;

    // initial fill: compiler loads + compiler waits (before any asm ops)
    float buf[PF];
    #pragma unroll
    for (int i = 0; i < PF; ++i) buf[i] = p[i * FCC];

    int t = t0;

    auto issue_loads = [&](float (&nbuf)[PF]) {
        const float* pf = (t + 2 * PF <= t_end) ? (p + PF * FCC) : p;
        #pragma unroll
        for (int i = 0; i < PF; ++i) {
            asm volatile("global_load_dword %0, %1, off"
                         : "=v"(nbuf[i]) : "v"(pf + i * FCC));
        }
        __builtin_amdgcn_sched_barrier(0);   // pin issue at group top
    };
    auto rcp_batch = [&](float (&rr)[PF], float (&ww)[PF]) {
        #pragma unroll
        for (int i = 0; i < PF; ++i) {
            const float bt = btg * BP[i];               // beta^(t+1+i)
            const float r  = __builtin_amdgcn_rcpf(1.0f - bt); // 1ulp; tol 0.1
            rr[i] = r;
            ww[i] = OMBF * r;
        }
        btg *= BP[PF];
    };
    auto step = [&](float x, float r, float w) -> float {
        v1 = fmaf(BETAF, v1, OMBF * x);                 // chain: 1 fma
        const float v2 = v1 * r;
        const float d  = x - v2;
        const float dp = x - v2p;
        S = fmaf(w, d * dp - S, S);                     // (1-w)*S + w*pr
        S = fmaxf(S, 0.0f);
        const float y = d * __builtin_amdgcn_rsqf(S + EPSF);
        v2p = v2;
        return y;
    };

    // ---- warm phase: whole group < t_out, no stores (y dead-codes away) ----
    while (t + PF <= t_out) {
        float nbuf[PF];
        issue_loads(nbuf);
        float rr[PF], ww[PF];
        rcp_batch(rr, ww);
        #pragma unroll
        for (int i = 0; i < PF; ++i) (void)step(buf[i], rr[i], ww[i]);
        asm volatile("s_waitcnt vmcnt(0)" ::: "memory");   // only loads in flight
        __builtin_amdgcn_sched_barrier(0);
        #pragma unroll
        for (int i = 0; i < PF; ++i) buf[i] = nbuf[i];
        p += PF * FCC; po += PF * FCC; t += PF;
    }

    // ---- boundary group (straddles t_out; at most one per chunk) ----
    while (t < t_out && t + PF <= t_end) {
        float nbuf[PF];
        issue_loads(nbuf);
        float rr[PF], ww[PF];
        rcp_batch(rr, ww);
        #pragma unroll
        for (int i = 0; i < PF; ++i) {
            const float y = step(buf[i], rr[i], ww[i]);
            if (t + i >= t_out) __builtin_nontemporal_store(y, po + i * FCC);
        }
        asm volatile("s_waitcnt vmcnt(0)" ::: "memory");   // conservative drain
        __builtin_amdgcn_sched_barrier(0);
        #pragma unroll
        for (int i = 0; i < PF; ++i) buf[i] = nbuf[i];
        p += PF * FCC; po += PF * FCC; t += PF;
    }

    // ---- output phase: 16 loads, 16 asm NT stores, counted wait ----
    while (t + PF <= t_end) {
        float nbuf[PF];
        issue_loads(nbuf);
        float rr[PF], ww[PF];
        rcp_batch(rr, ww);
        #pragma unroll
        for (int i = 0; i < PF; ++i) {
            const float y = step(buf[i], rr[i], ww[i]);
            // volatile asm store: cannot reorder vs the volatile asm loads ->
            // the 16 loads are the oldest VMEM ops of this group.
            asm volatile("global_store_dword %0, %1, off nt"
                         :: "v"(po + i * FCC), "v"(y));
        }
        // completes this group's 16 loads (+ last group's store leftovers);
        // leaves this group's 16 stores in flight. Never drains stores.
        asm volatile("s_waitcnt vmcnt(16)" ::: "memory");
        __builtin_amdgcn_sched_barrier(0);
        #pragma unroll
        for (int i = 0; i < PF; ++i) buf[i] = nbuf[i];
        p += PF * FCC; po += PF * FCC; t += PF;
    }

    // ---- tail (< PF steps): compiler loads/stores, compiler waits ----
    for (; t < t_end; ++t) {
        const float x  = *p;
        const float r  = __builtin_amdgcn_rcpf(1.0f - btg);
        const float w  = OMBF * r;
        btg *= BETAF;
        v1 = fmaf(BETAF, v1, OMBF * x);
        const float v2 = v1 * r;
        const float d  = x - v2;
        const float dp = x - v2p;
        S = fmaf(w, d * dp - S, S);
        S = fmaxf(S, 0.0f);
        const float y = d * __builtin_amdgcn_rsqf(S + EPSF);
        v2p = v2;
        if (t >= t_out) __builtin_nontemporal_store(y, po);
        p  += FCC;
        po += FCC;
    }
}

extern "C" void kernel_launch(void* const* d_in, const int* in_sizes, int n_in,
                              void* d_out, int out_size, void* d_ws, size_t ws_size,
                              hipStream_t stream) {
    const float* s = (const float*)d_in[0];
    float* out = (float*)d_out;
    dim3 grid((SERIES + 63) / 64, NCHUNK);   // 129 x 7 blocks of 64
    ewma_kernel<<<grid, dim3(64), 0, stream>>>(s, out);
}

// Round 9
// 144.707 us; speedup vs baseline: 1.1418x; 1.0407x over previous
//
#include <hip/hip_runtime.h>

// Problem: unbiased EWMA mean/var normalization over T, s:(16,2000,257,2) fp32.
// Layout: idx = ((n*T + t)*F + f)*C + c  ->  series stride over t is F*C = 514.
//
// Strategy (v9 — depth-2 pipeline via global_load_lds; no load dest regs):
//  - One thread per (n,f,c) series; sequential over t (S>0 clamp breaks scan
//    associativity). NCHUNK=7, CLEN=286, WARM=512. 903 waves, 64-thr blocks.
//  - v7/v8 post-mortem (core dumps): an inline-asm global_load whose dest
//    VGPR stays pending ACROSS a loop backedge is an allocator hazard: the
//    compiler models the write at the asm statement, may insert copies at
//    control-flow merges and reuse the physical register (e.g. for updated
//    pointers); the late-returning DMA then clobbers a live pointer -> page
//    fault. Lesson: deep load pipelining must go through LDS (no dest reg).
//  - v9 pipeline, per group g of PF=16 steps (buffers: lds[g&1]):
//      0. deferred stores of group g-1's y (issued at group TOP, right after
//         the previous wait -> a full compute block of L2-ack slack; plain
//         compiler stores, predicate is wave-uniform, auto-false on each
//         chunk's first group)
//      1. asm ds_read_b32 x[0..15] from lds[par]; lgkmcnt(0); sched_barrier
//         (asm outputs consumed immediately -- the v4/v5-proven safe window)
//      2. stage group g+2 into lds[par] (just freed): 16x
//         __builtin_amdgcn_global_load_lds(src, dst, 4, 0, 0)
//         - per-lane global src (own series elem), uniform LDS base + lane*4
//         - no VGPR destination => no allocator hazard, ever
//      3. rr batch (16 pipelined v_rcp) + 16 steps -> yprev
//      4. s_waitcnt vmcnt(16): 16 = stage(g+2). Loads retire in order among
//         loads => stage(g+1) (needed next group) guaranteed complete;
//         store-acks cannot fake this guarantee, only lengthen the wait.
//         Queue peak: stage(g+1)16 + stores16 + stage(g+2)16 = 48 < 63
//         (vmcnt is 6-bit; v6's 64-deep queue overflowed it -> NaN).
//    => stage(g+1) is in flight for a FULL group period + compute: depth 2.
//  - Lane-invariant r=1/(1-beta^{t+1}), w=(1-beta)*r batched per group.
//  - __launch_bounds__(64,1): full VGPR budget (v1-v3: a 24-VGPR allocation
//    re-sank all prefetches to just-in-time loads at 222 cyc/step).

#define NN 16
#define TT 2000
#define FCC 514               // F*C
#define SERIES (NN * FCC)     // 8224
#define BETAF 0.99f
#define OMBF 0.01f            // 1 - beta
#define EPSF 1e-5f
#define NCHUNK 7
#define CLEN 286              // ceil(2000/7)
#define WARM 512
#define PF 16

// beta^i, i=0..16 (folds to literals)
__device__ __constant__ const float BP[PF + 1] = {
    1.0f,
    0.99f,
    0.9801f,
    0.970299f,
    0.96059601f,
    0.9509900499f,
    0.941480149401f,
    0.93206534790699f,
    0.9227446944279201f,
    0.9134272474836409f,
    0.9042929750088045f,
    0.8952500452587165f,
    0.8862975448061293f,
    0.877434569357868f,
    0.8686602236642894f,
    0.8599736214276465f,
    0.8513738852133700f   // beta^16 (per-group btg advance)
};

// global (addrspace 1) -> LDS (addrspace 3) direct DMA, 4B per lane.
// LDS dest: wave-uniform base, HW adds lane*4. Global src: per-lane address.
__device__ __forceinline__ void ld_lds(const float* g, float* l) {
    __builtin_amdgcn_global_load_lds(
        (const __attribute__((address_space(1))) void*)g,
        (__attribute__((address_space(3))) void*)l, 4, 0, 0);
}

__global__ __launch_bounds__(64, 1)
void ewma_kernel(const float* __restrict__ s, float* __restrict__ out) {
    __shared__ float lds[2][PF][64];   // [buffer][step-in-group][lane] = 8 KB

    const int lane = threadIdx.x;
    const int tid  = blockIdx.x * 64 + lane;
    if (tid >= SERIES) return;         // block 128: lanes 32-63 exit (exec-masked)

    const int chunk = blockIdx.y;
    const int t_out = chunk * CLEN;
    int t_end = t_out + CLEN; if (t_end > TT) t_end = TT;
    int t0 = t_out - WARM;     if (t0 < 0) t0 = 0;

    const int n  = tid / FCC;
    const int fc = tid - n * FCC;

    // btg = beta^(t0+1) via double binary exponentiation (once per thread)
    double bd = 0.99, acc = 0.99;       // acc starts at beta^1
    int e = t0;
    while (e) { if (e & 1) acc *= bd; bd *= bd; e >>= 1; }
    float btg = (float)acc;             // beta^(t+1) for the group's first step

    float v1 = 0.0f, v2p = 0.0f, S = 0.0f;

    const size_t base = (size_t)n * TT * FCC + (size_t)fc + (size_t)t0 * FCC;
    const float* p  = s   + base;
    float*       po = out + base;

    // 32-bit LDS byte address of this lane's slot (as3 pointers are 32-bit)
    __attribute__((address_space(3))) float* l3 =
        (__attribute__((address_space(3))) float*)&lds[0][0][lane];
    const unsigned lbase = (unsigned)(uintptr_t)l3;

    // ---- prologue: stage groups 0 and 1 (span >= CLEN >= 2*PF always) ----
    #pragma unroll
    for (int i = 0; i < PF; ++i) ld_lds(p + i * FCC,        &lds[0][i][0]);
    #pragma unroll
    for (int i = 0; i < PF; ++i) ld_lds(p + (PF + i) * FCC, &lds[1][i][0]);
    // sound: 16 loads younger than stage(0) -> stage(0) complete after this
    asm volatile("s_waitcnt vmcnt(16)" ::: "memory");
    __builtin_amdgcn_sched_barrier(0);

    float yprev[PF];
    #pragma unroll
    for (int i = 0; i < PF; ++i) yprev[i] = 0.0f;

    int t = t0;
    int par = 0;
    while (t + PF <= t_end) {
        // ---- 0. deferred stores of group g-1 (max in-queue ack slack);
        //         predicate auto-false on each chunk's first group ----
        #pragma unroll
        for (int i = 0; i < PF; ++i)
            if (t - PF + i >= t_out) po[(i - PF) * FCC] = yprev[i];

        // ---- 1. read group g's x from lds[par] (asm: opaque to compiler,
        //         so it cannot insert its own vmcnt waits or hoist) ----
        float x[PF];
        const unsigned abase = lbase + (unsigned)par * (PF * 256);
        #pragma unroll
        for (int i = 0; i < PF; ++i)
            asm volatile("ds_read_b32 %0, %1"
                         : "=v"(x[i]) : "v"(abase + (unsigned)(i * 256)));
        asm volatile("s_waitcnt lgkmcnt(0)" ::: "memory");
        __builtin_amdgcn_sched_barrier(0);   // rule #18: pin consumers below

        // ---- 2. stage group g+2 into lds[par] (just freed) ----
        {
            const float* gsrc = (t + 3 * PF <= t_end) ? (p + 2 * PF * FCC) : p;
            #pragma unroll
            for (int i = 0; i < PF; ++i) ld_lds(gsrc + i * FCC, &lds[par][i][0]);
        }

        // ---- 3. per-group scalars + 16 steps ----
        float rr[PF];
        #pragma unroll
        for (int i = 0; i < PF; ++i)
            rr[i] = __builtin_amdgcn_rcpf(1.0f - btg * BP[i]);  // 1ulp; tol 0.1
        btg *= BP[PF];
        #pragma unroll
        for (int i = 0; i < PF; ++i) {
            const float xx = x[i];
            const float r  = rr[i];
            const float w  = OMBF * r;
            v1 = fmaf(BETAF, v1, OMBF * xx);            // chain: 1 fma
            const float v2 = v1 * r;
            const float d  = xx - v2;
            const float dp = xx - v2p;
            S = fmaf(w, d * dp - S, S);                 // (1-w)*S + w*pr
            S = fmaxf(S, 0.0f);
            yprev[i] = d * __builtin_amdgcn_rsqf(S + EPSF);
            v2p = v2;
        }

        // ---- 4. sound depth-2 wait: stage(g+1) complete; peak queue 48 ----
        asm volatile("s_waitcnt vmcnt(16)" ::: "memory");
        __builtin_amdgcn_sched_barrier(0);

        par ^= 1;
        p += PF * FCC; po += PF * FCC; t += PF;
    }

    // ---- flush last group's outputs ----
    #pragma unroll
    for (int i = 0; i < PF; ++i)
        if (t - PF + i >= t_out) po[(i - PF) * FCC] = yprev[i];

    // drain all LDS-DMA before the tail / endpgm
    asm volatile("s_waitcnt vmcnt(0)" ::: "memory");
    __builtin_amdgcn_sched_barrier(0);

    // ---- scalar tail (< PF steps), fully compiler-managed ----
    for (; t < t_end; ++t) {
        const float xx = *p;
        const float r  = __builtin_amdgcn_rcpf(1.0f - btg);
        const float w  = OMBF * r;
        btg *= BETAF;
        v1 = fmaf(BETAF, v1, OMBF * xx);
        const float v2 = v1 * r;
        const float d  = xx - v2;
        const float dp = xx - v2p;
        S = fmaf(w, d * dp - S, S);
        S = fmaxf(S, 0.0f);
        const float y = d * __builtin_amdgcn_rsqf(S + EPSF);
        v2p = v2;
        if (t >= t_out) *po = y;
        p  += FCC;
        po += FCC;
    }
}

extern "C" void kernel_launch(void* const* d_in, const int* in_sizes, int n_in,
                              void* d_out, int out_size, void* d_ws, size_t ws_size,
                              hipStream_t stream) {
    const float* s = (const float*)d_in[0];
    float* out = (float*)d_out;
    dim3 grid((SERIES + 63) / 64, NCHUNK);   // 129 x 7 blocks of 64
    ewma_kernel<<<grid, dim3(64), 0, stream>>>(s, out);
}